// Round 10
// baseline (2638.374 us; speedup 1.0000x reference)
//
#include <hip/hip_runtime.h>
#include <hip/hip_bf16.h>

// ModalityEnhancedLSTM: B=64, S=1024, D=256, H=256.
// out = [hidden_seq (64*1024*256) | h_t (64*256) | c_t (64*256)] f32.
//
//  prep_kernel : W -> bf16 B-frag layout; U -> NEGATED bf16 B-frag layout
//                (MFMA((-h),(-U)) == h@U; writers store -h => nonzero bf16
//                pattern => data-is-the-flag poll, no separate flags).
//  xproj_kernel: xp = x@W + bias, bf16, [wg][t][slice][lane][4] layout.
//  lstm_kernel : TICKET-BASED SELF-PLACEMENT (proven r9): grid 1024; WGs on
//                XCD<4 take a per-XCD ticket; first 8 on XCD g = group g's
//                colWGs. Same-XCD grouping BY CONSTRUCTION.
//                10 waves: w0-7 compute, w8 xp service, w9 slow publisher.
//                Dual publish: gate lanes 2B sc0 (XCD-L2 fast) + w9 16B
//                sc0 sc1 (L3 slow). ROUND-10 FIX: fast poll is NON-STICKY
//                with adaptive budget K (success: K+=2 to 16; miss: K/=2 to
//                2, finish step on slow poll, RETRY fast next step). Round
//                9's sticky-off was a cascade trap: one 12-iter miss at any
//                of 65536 wave-steps permanently disabled that wave's fast
//                path and dragged its readers into misses -> all-slow within
//                a few steps -> fast path never actually benchmarked.
//                Liveness: slow poll unconditional + 4M-iteration bail.

#define BSH 16777216u   // 64*1024*256
#define BH  16384u

typedef short short8 __attribute__((ext_vector_type(8)));
typedef float float4_ __attribute__((ext_vector_type(4)));
typedef unsigned int uint2_ __attribute__((ext_vector_type(2)));
typedef unsigned int uint4_ __attribute__((ext_vector_type(4)));

static __device__ __forceinline__ unsigned short f2bf(float f) {
    unsigned int u = __builtin_bit_cast(unsigned int, f);
    u += 0x7FFFu + ((u >> 16) & 1u);
    return (unsigned short)(u >> 16);
}
static __device__ __forceinline__ float bf2f(unsigned short h) {
    unsigned int u = ((unsigned int)h) << 16;
    return __builtin_bit_cast(float, u);
}
static __device__ __forceinline__ uint4_ pack8(const unsigned short* t) {
    uint4_ v;
    v.x = (unsigned int)t[0] | ((unsigned int)t[1] << 16);
    v.y = (unsigned int)t[2] | ((unsigned int)t[3] << 16);
    v.z = (unsigned int)t[4] | ((unsigned int)t[5] << 16);
    v.w = (unsigned int)t[6] | ((unsigned int)t[7] << 16);
    return v;
}
static __device__ __forceinline__ unsigned umin_(unsigned a, unsigned b) {
    return a < b ? a : b;
}
static __device__ __forceinline__ unsigned pkmin16(unsigned a, unsigned b) {
    unsigned d;
    asm("v_pk_min_u16 %0, %1, %2" : "=v"(d) : "v"(a), "v"(b));
    return d;
}
static __device__ __forceinline__ void gload_lds16(const void* g, void* l) {
    __builtin_amdgcn_global_load_lds(
        (const __attribute__((address_space(1))) unsigned int*)g,
        (__attribute__((address_space(3))) unsigned int*)l, 16, 0, 0);
}
static __device__ __forceinline__ void barrier_lgkm() {
    asm volatile("s_waitcnt lgkmcnt(0)" ::: "memory");
    __builtin_amdgcn_s_barrier();
    asm volatile("" ::: "memory");
}

// ---------------- prep: W,(-U) -> bf16 frag layout; bias -> per-slice -------
__global__ void prep_kernel(const float* __restrict__ W, const float* __restrict__ U,
                            const float* __restrict__ bias,
                            unsigned short* __restrict__ Wbf, unsigned short* __restrict__ Ubf,
                            float* __restrict__ biasf) {
    int tid = blockIdx.x * blockDim.x + threadIdx.x;
    if (tid < 65536) {
        int idx = tid & 32767;
        const bool isU = (tid >= 32768);
        const float* src = isU ? U : W;
        unsigned short* dst = isU ? Ubf : Wbf;
        int sl = idx >> 9, kt = (idx >> 6) & 7, lane = idx & 63;
        int c = lane & 15, kgrp = lane >> 4;
        int m = sl >> 3, wv = sl & 7;
        int gatec = c >> 2, jj = c & 3;
        int ncol = gatec * 256 + 32 * m + 4 * wv + jj;
        unsigned short t8[8];
#pragma unroll
        for (int e = 0; e < 8; e++) {
            int k = kt * 32 + kgrp * 8 + e;
            float v = src[k * 1024 + ncol];
            t8[e] = f2bf(isU ? -v : v);
        }
        *(uint4_*)(dst + (size_t)idx * 8) = pack8(t8);
    } else if (tid < 66560) {
        int idx2 = tid - 65536;            // [0,1024)
        int sl = idx2 >> 4, c = idx2 & 15;
        int m = sl >> 3, wv = sl & 7, gatec = c >> 2, jj = c & 3;
        int ncol = gatec * 256 + 32 * m + 4 * wv + jj;
        biasf[idx2] = bias[ncol];
    }
}

// ---------------- xproj: xp = x @ W + bias, bf16, per-WG layout -------------
__global__ __launch_bounds__(512, 2)
void xproj_kernel(const float* __restrict__ x, const unsigned short* __restrict__ Wbf,
                  const float* __restrict__ biasf, unsigned short* __restrict__ xp) {
    const int bx = blockIdx.x;             // [0,1024)
    const int g = bx & 3, tile = bx >> 2;  // 256 tiles of 4 s each
    const int s0 = tile * 4;
    const int tidx = threadIdx.x;
    const int w = tidx >> 6, lane = tidx & 63;

    __shared__ unsigned short Afrag[4][8][64][8];  // [si][kt][lane][e] 32KB

    {   // stage x (f32 -> bf16 A-frags)
        int row = tidx >> 3;               // 0..63 = si*16 + r
        int kt = tidx & 7;
        int si = row >> 4, r = row & 15;
        int b = g * 16 + r, s = s0 + si;
        const float* px = x + ((size_t)b * 1024 + s) * 256 + kt * 32;
#pragma unroll
        for (int kg = 0; kg < 4; kg++) {
            float4_ v0 = *(const float4_*)(px + kg * 8);
            float4_ v1 = *(const float4_*)(px + kg * 8 + 4);
            unsigned short t8[8] = { f2bf(v0.x), f2bf(v0.y), f2bf(v0.z), f2bf(v0.w),
                                     f2bf(v1.x), f2bf(v1.y), f2bf(v1.z), f2bf(v1.w) };
            *(uint4_*)&Afrag[si][kt][kg * 16 + r][0] = pack8(t8);
        }
    }
    __syncthreads();

    float4_ acc[8][4];
#pragma unroll
    for (int q = 0; q < 8; q++) {
        int sl = w * 8 + q;
        float bv = biasf[sl * 16 + (lane & 15)];
#pragma unroll
        for (int si = 0; si < 4; si++) acc[q][si] = (float4_){bv, bv, bv, bv};
    }
#pragma unroll
    for (int kt = 0; kt < 8; kt++) {
        short8 a[4];
#pragma unroll
        for (int si = 0; si < 4; si++)
            a[si] = *(const short8*)&Afrag[si][kt][lane][0];
#pragma unroll
        for (int q = 0; q < 8; q++) {
            short8 bfr = *(const short8*)(Wbf + (((size_t)(w * 8 + q) * 8 + kt) * 64 + lane) * 8);
#pragma unroll
            for (int si = 0; si < 4; si++)
                acc[q][si] = __builtin_amdgcn_mfma_f32_16x16x32_bf16(a[si], bfr, acc[q][si], 0, 0, 0);
        }
    }
#pragma unroll
    for (int q = 0; q < 8; q++) {
        int sl = w * 8 + q;
        int wgx = g * 8 + (sl >> 3);
#pragma unroll
        for (int si = 0; si < 4; si++) {
            int s = s0 + si;
            unsigned int lo = (unsigned int)f2bf(acc[q][si].x) | ((unsigned int)f2bf(acc[q][si].y) << 16);
            unsigned int hi = (unsigned int)f2bf(acc[q][si].z) | ((unsigned int)f2bf(acc[q][si].w) << 16);
            uint2_ v = {lo, hi};
            *(uint2_*)(xp + ((((size_t)wgx * 1024 + s) * 8 + (sl & 7)) * 64 + lane) * 4) = v;
        }
    }
}

// ---------------- recurrent scan -------------------------------------------
__global__ __launch_bounds__(640, 1)
void lstm_kernel(const unsigned short* __restrict__ Ubf,
                 const unsigned short* __restrict__ xp,
                 const float* __restrict__ lam,
                 unsigned short* __restrict__ hslow,  // zero-initialized, sc0 sc1
                 unsigned short* __restrict__ hfast,  // zero-initialized, sc0 (may be null)
                 unsigned int* __restrict__ ticket,   // zero-initialized, 4 u32
                 float* __restrict__ out) {
    const int tid = threadIdx.x;
    const int w = tid >> 6, lane = tid & 63;

    __shared__ int roleLDS[2];
    __shared__ float lamLDS[1024];
    __shared__ alignas(16) unsigned short htmp[2][16][40];     // -h bf16 (zeroed)
    __shared__ alignas(16) unsigned short xpring[8][2048];     // xp ring
    __shared__ alignas(16) unsigned short hstage[2][8][64][8]; // staged h blocks

    // --- ticket-based self-placement: group = my XCD, m = arrival rank ------
    if (tid == 0) {
        unsigned xcd;
        asm volatile("s_getreg_b32 %0, hwreg(HW_REG_XCC_ID)" : "=s"(xcd));
        xcd &= 7u;
        unsigned tk = 0xFFu;
        if (xcd < 4u)
            tk = __hip_atomic_fetch_add(&ticket[xcd], 1u,
                                        __ATOMIC_RELAXED, __HIP_MEMORY_SCOPE_AGENT);
        roleLDS[0] = (int)xcd;
        roleLDS[1] = (int)tk;
    }
    __syncthreads();
    const int g = roleLDS[0];
    const int m = roleLDS[1];
    if (g >= 4 || m >= 8) return;          // surplus WG: free the CU

    ((unsigned int*)htmp)[tid] = 0u;       // 640 dwords = 2560B exactly
    for (int i = tid; i < 1024; i += 640) lamLDS[i] = lam[i];

    const int col = lane & 15;
    const int gatec = col >> 2, jj = col & 3;
    const int rr0 = (lane >> 4) * 4;
    const bool active = (gatec == 0);
    const bool fast_en = (hfast != nullptr);

    short8 u[8];
    if (w < 8) {
        int sl = m * 8 + w;
#pragma unroll
        for (int kt = 0; kt < 8; kt++)
            u[kt] = *(const short8*)(Ubf + (((size_t)sl * 8 + kt) * 64 + lane) * 8);
    }

    const size_t wgx = (size_t)(g * 8 + m);

    if (w == 8) {   // prologue: prefetch xp steps 0..5
        for (int s = 0; s < 6; s++) {
            const char* src = (const char*)xp + ((wgx * 1024 + s) << 12) + (size_t)lane * 16;
            char* dst = (char*)&xpring[s][0];
#pragma unroll
            for (int c2 = 0; c2 < 4; c2++)
                gload_lds16(src + c2 * 1024, dst + c2 * 1024);
        }
        asm volatile("s_waitcnt vmcnt(20)" ::: "memory");   // slot 0 ready
    }

    float cst[4] = {0.f, 0.f, 0.f, 0.f};
    barrier_lgkm();

    // gate-lane FAST publish base (t=0): element (row rr0, col u_col), block m
    const int u_col = 4 * w + jj;
    char* hpubF = (char*)hfast + ((size_t)g << 13) + (size_t)m * 1024
                + (size_t)((u_col >> 3) * 256 + rr0 * 16 + (u_col & 7) * 2);
    // reader poll pointers (slot t-1), advanced at loop end
    const char* pf = (const char*)hfast + ((size_t)g << 13) + (size_t)w * 1024
                   + (size_t)lane * 16 - 32768;
    const char* pb = (const char*)hslow + ((size_t)g << 13) + (size_t)w * 1024
                   + (size_t)lane * 16 - 32768;
    // publisher (w9) slow-store base (slot t)
    char* hps = (char*)hslow + ((size_t)g << 13) + (size_t)m * 1024 + (size_t)lane * 16;

    int K = 8;   // adaptive per-step fast-poll budget (wave-uniform)

    for (int t = 0; t < 1024; t++) {
        // ---------- pre-barrier: poll + stage (minimal critical path) -------
        if (w < 8) {
            if (t > 0) {
                uint4_ r;
                bool got = false;
                if (fast_en) {
                    for (int k = 0; k < K; k++) {
                        asm volatile("global_load_dwordx4 %0, %1, off sc0\n\t"
                                     "s_waitcnt vmcnt(0)"
                                     : "=v"(r) : "v"(pf) : "memory");
                        __builtin_amdgcn_sched_barrier(0);
                        unsigned mm = pkmin16(pkmin16(r.x, r.y), pkmin16(r.z, r.w));
                        if (__all(((mm & 0xffffu) != 0u) && ((mm >> 16) != 0u))) {
                            got = true; break;
                        }
                    }
                    // NON-STICKY adaptation: back off on miss, recover on hit.
                    K = got ? (K < 16 ? K + 2 : 16) : (K > 2 ? (K >> 1) : 2);
                }
                if (!got) {
                    unsigned bail = 0;
                    for (;;) {   // PROVEN slow poll: per-dword nonzero; bounded
                        asm volatile("global_load_dwordx4 %0, %1, off sc0 sc1\n\t"
                                     "s_waitcnt vmcnt(0)"
                                     : "=v"(r) : "v"(pb) : "memory");
                        __builtin_amdgcn_sched_barrier(0);
                        if (__all(umin_(umin_(r.x, r.y), umin_(r.z, r.w)) != 0u)) break;
                        if (++bail > (1u << 22)) break;    // fail fast, never hang
                    }
                }
                *(uint4_*)&hstage[t & 1][w][lane][0] = r;   // ds_write_b128
            }
        } else if (w == 8) {
            if (t + 6 < 1024) {
                int slot = (t + 6) & 7;
                const char* src = (const char*)xp + ((wgx * 1024 + (size_t)(t + 6)) << 12)
                                  + (size_t)lane * 16;
                char* dst = (char*)&xpring[slot][0];
#pragma unroll
                for (int c2 = 0; c2 < 4; c2++)
                    gload_lds16(src + c2 * 1024, dst + c2 * 1024);
            }
            if (t == 0)            asm volatile("s_waitcnt vmcnt(20)" ::: "memory");
            else if (t == 1)       asm volatile("s_waitcnt vmcnt(22)" ::: "memory");
            else if (t + 6 < 1024) asm volatile("s_waitcnt vmcnt(24)" ::: "memory");
            else                   asm volatile("s_waitcnt vmcnt(0)"  ::: "memory");
        }
        barrier_lgkm();
        // ---------- post-barrier ----------
        if (w < 8) {
            unsigned long long xpd =
                *(const unsigned long long*)&xpring[t & 7][w * 256 + lane * 4];
            float4_ acc0, acc1 = (float4_){0.f, 0.f, 0.f, 0.f};
            acc0.x = bf2f((unsigned short)(xpd & 0xffff));
            acc0.y = bf2f((unsigned short)((xpd >> 16) & 0xffff));
            acc0.z = bf2f((unsigned short)((xpd >> 32) & 0xffff));
            acc0.w = bf2f((unsigned short)(xpd >> 48));

            if (t > 0) {
                short8 a0 = *(const short8*)&hstage[t & 1][0][lane][0];
                short8 a1 = *(const short8*)&hstage[t & 1][1][lane][0];
                short8 a2 = *(const short8*)&hstage[t & 1][2][lane][0];
                short8 a3 = *(const short8*)&hstage[t & 1][3][lane][0];
                short8 a4 = *(const short8*)&hstage[t & 1][4][lane][0];
                short8 a5 = *(const short8*)&hstage[t & 1][5][lane][0];
                short8 a6 = *(const short8*)&hstage[t & 1][6][lane][0];
                short8 a7 = *(const short8*)&hstage[t & 1][7][lane][0];
                acc0 = __builtin_amdgcn_mfma_f32_16x16x32_bf16(a0, u[0], acc0, 0, 0, 0);
                acc1 = __builtin_amdgcn_mfma_f32_16x16x32_bf16(a1, u[1], acc1, 0, 0, 0);
                acc0 = __builtin_amdgcn_mfma_f32_16x16x32_bf16(a2, u[2], acc0, 0, 0, 0);
                acc1 = __builtin_amdgcn_mfma_f32_16x16x32_bf16(a3, u[3], acc1, 0, 0, 0);
                acc0 = __builtin_amdgcn_mfma_f32_16x16x32_bf16(a4, u[4], acc0, 0, 0, 0);
                acc1 = __builtin_amdgcn_mfma_f32_16x16x32_bf16(a5, u[5], acc1, 0, 0, 0);
                acc0 = __builtin_amdgcn_mfma_f32_16x16x32_bf16(a6, u[6], acc0, 0, 0, 0);
                acc1 = __builtin_amdgcn_mfma_f32_16x16x32_bf16(a7, u[7], acc1, 0, 0, 0);
            }

            float lamt = lamLDS[t];
            float gv[4], fv[4], ggv[4], ov[4];
#pragma unroll
            for (int q = 0; q < 4; q++) {
                float xg = acc0[q] + acc1[q];
                float y = (gatec == 2) ? 2.f * xg : xg;
                float sgm = 1.f / (1.f + __expf(-y));
                gv[q] = (gatec == 2) ? 2.f * sgm - 1.f : sgm;
            }
#pragma unroll
            for (int q = 0; q < 4; q++) {
                fv[q]  = __shfl(gv[q], lane + 4, 64);
                ggv[q] = __shfl(gv[q], lane + 8, 64);
                ov[q]  = __shfl(gv[q], lane + 12, 64);
            }
            if (active) {
                float hq[4];
                unsigned short hb[4];
#pragma unroll
                for (int q = 0; q < 4; q++) {
                    float c = fv[q] * cst[q] + gv[q] * ggv[q] * lamt;
                    cst[q] = c;
                    float th = 2.f / (1.f + __expf(-2.f * c)) - 1.f;
                    hq[q] = ov[q] * th;
                    unsigned short b = f2bf(-hq[q]);
                    if (b == 0) b = 0x8000u;   // -0.0: numerically 0, bits != 0
                    hb[q] = b;
                }
                // FAST publish straight from registers (same-XCD L2 visibility)
                if (fast_en) {
                    asm volatile("global_store_short %0, %1, off sc0"           :: "v"(hpubF), "v"((unsigned)hb[0]) : "memory");
                    asm volatile("global_store_short %0, %1, off offset:16 sc0" :: "v"(hpubF), "v"((unsigned)hb[1]) : "memory");
                    asm volatile("global_store_short %0, %1, off offset:32 sc0" :: "v"(hpubF), "v"((unsigned)hb[2]) : "memory");
                    asm volatile("global_store_short %0, %1, off offset:48 sc0" :: "v"(hpubF), "v"((unsigned)hb[3]) : "memory");
                }
#pragma unroll
                for (int q = 0; q < 4; q++)
                    htmp[t & 1][rr0 + q][4 * w + jj] = hb[q];
                if (t == 1023) {
#pragma unroll
                    for (int q = 0; q < 4; q++) {
                        size_t b = (size_t)g * 16 + rr0 + q;
                        int j = m * 32 + 4 * w + jj;
                        out[BSH + b * 256 + j] = hq[q];
                        out[BSH + BH + b * 256 + j] = cst[q];
                    }
                }
            }
        } else if (w == 9) {
            // publisher: LDS-poll htmp[t&1] complete, then slow-publish (sc0 sc1)
            // + hidden_seq f32 + zero htmp[t&1] for reuse at t+2.
            int r_ = lane & 15, kg = lane >> 4;
            volatile unsigned int* hp32 =
                (volatile unsigned int*)&htmp[t & 1][r_][kg * 8];
            unsigned a0, a1, a2, a3;
            for (;;) {
                a0 = hp32[0]; a1 = hp32[1]; a2 = hp32[2]; a3 = hp32[3];
                unsigned mm = pkmin16(pkmin16(a0, a1), pkmin16(a2, a3));
                if (__all(((mm & 0xffffu) != 0u) && ((mm >> 16) != 0u))) break;
            }
            uint4_ blk = {a0, a1, a2, a3};
            asm volatile("global_store_dwordx4 %0, %1, off sc0 sc1"
                         :: "v"(hps), "v"(blk) : "memory");
            // hidden_seq: -(-h) = h, bf16 -> f32
            unsigned x0 = a0 ^ 0x80008000u, x1 = a1 ^ 0x80008000u;
            unsigned x2 = a2 ^ 0x80008000u, x3 = a3 ^ 0x80008000u;
            float4_ v0 = { bf2f((unsigned short)(x0 & 0xffff)), bf2f((unsigned short)(x0 >> 16)),
                           bf2f((unsigned short)(x1 & 0xffff)), bf2f((unsigned short)(x1 >> 16)) };
            float4_ v1 = { bf2f((unsigned short)(x2 & 0xffff)), bf2f((unsigned short)(x2 >> 16)),
                           bf2f((unsigned short)(x3 & 0xffff)), bf2f((unsigned short)(x3 >> 16)) };
            float* po = out + (((size_t)(g * 16 + r_)) << 18) + ((size_t)t << 8)
                        + m * 32 + kg * 8;
            *(float4_*)po = v0;
            *(float4_*)(po + 4) = v1;
            // zero for step t+2 (two barriers away from its next writes)
            uint4_ z = {0u, 0u, 0u, 0u};
            *(uint4_*)&htmp[t & 1][r_][kg * 8] = z;
        }
        pf += 32768;
        pb += 32768;
        hpubF += 32768;
        hps += 32768;
    }
}

__global__ void ws_too_small_kernel(float* out) {
    if (threadIdx.x == 0 && blockIdx.x == 0) out[0] = -777777.0f;
}

extern "C" void kernel_launch(void* const* d_in, const int* in_sizes, int n_in,
                              void* d_out, int out_size, void* d_ws, size_t ws_size,
                              hipStream_t stream) {
    const float* x    = (const float*)d_in[0];
    const float* lam  = (const float*)d_in[1];
    const float* W    = (const float*)d_in[2];
    const float* U    = (const float*)d_in[3];
    const float* bias = (const float*)d_in[4];
    float* out = (float*)d_out;

    const size_t NEED_BASE = (size_t)162 << 20;  // 2MiB prep + 32MiB hslow + 128MiB xp
    const size_t NEED_FAST = (size_t)194 << 20;  // + 32MiB hfast
    if (ws_size < NEED_BASE) {
        ws_too_small_kernel<<<1, 64, 0, stream>>>(out);
        return;
    }
    const bool fast_en = (ws_size >= NEED_FAST);
    char* ws = (char*)d_ws;
    unsigned int*   ticket = (unsigned int*)ws;                        // 16B used
    unsigned short* Ubf   = (unsigned short*)(ws + (256 << 10));       // 512KB
    unsigned short* Wbf   = (unsigned short*)(ws + (768 << 10));       // 512KB
    float*          biasf = (float*)(ws + (1280 << 10));               // 4KB
    unsigned short* hslow = (unsigned short*)(ws + ((size_t)2 << 20)); // 32MiB
    unsigned short* xp    = (unsigned short*)(ws + ((size_t)66 << 20));// 128MiB
    unsigned short* hfast = fast_en ? (unsigned short*)(ws + ((size_t)34 << 20)) : nullptr;

    hipMemsetAsync(ticket, 0, 64, stream);
    hipMemsetAsync(hslow, 0, (size_t)32 << 20, stream);   // slow sentinel
    if (fast_en)
        hipMemsetAsync(hfast, 0, (size_t)32 << 20, stream);  // fast sentinel
    prep_kernel<<<260, 256, 0, stream>>>(W, U, bias, Wbf, Ubf, biasf);
    xproj_kernel<<<1024, 512, 0, stream>>>(x, Wbf, biasf, xp);
    lstm_kernel<<<1024, 640, 0, stream>>>(Ubf, xp, lam, hslow, hfast, ticket, out);
}